// Round 5
// baseline (397.453 us; speedup 1.0000x reference)
//
#include <hip/hip_runtime.h>

// irreps linear: 256x0e + 128x1o + 64x2e, shared weights, bias on 0e.
// x: (200000, 960) f32; w: 86016 f32; b: 256 f32; out: (200000, 960) f32.
//
// Round 5 = Round 4 structure (per-(tile,family) blocks, global_load_lds
// staging, XOR chunk swizzle, vectorized cached stores) with the bf16
// conversion rewritten from scalar bit-twiddle f2bf (~4-5 VALU/elem) to
// v_cvt_pk_bf16_f32 (1 VALU per 2 elems), pairs chosen to build each packed
// fragment register directly. Theory: R1/R4 both plateau at ~4 TB/s because
// the f2bf chains oversubscribe the VALU; cvt_pk cuts conversion VALU ~8x.

typedef short frag8 __attribute__((ext_vector_type(8)));   // 8 bf16
typedef float f32x4 __attribute__((ext_vector_type(4)));
typedef unsigned int u32;
typedef u32 u32x4 __attribute__((ext_vector_type(4)));

static __device__ __forceinline__ short f2bf(float f) {   // prep kernel only
    union { float f; unsigned u; } v; v.f = f;
    unsigned r = (v.u + 0x7FFFu + ((v.u >> 16) & 1u)) >> 16;  // RNE
    return (short)r;
}

// 2 f32 -> one u32 holding 2 bf16 (lo = first arg), single VALU op.
static __device__ __forceinline__ u32 cvtpk(float lo, float hi) {
    u32 r;
    asm("v_cvt_pk_bf16_f32 %0, %1, %2" : "=v"(r) : "v"(lo), "v"(hi));
    return r;
}

static __device__ __forceinline__ frag8 asfrag(u32x4 u) {
    union { u32x4 u; frag8 f; } t; t.u = u; return t.f;
}

#define MFMA(a, b, c) __builtin_amdgcn_mfma_f32_16x16x32_bf16((a), (b), (c), 0, 0, 0)

// ---- weight prep: unchanged (validated rounds 1-4). frag f, lane l, reg j:
// k = 32*s + 4*(l>>4) + (j&3) + 16*(j>>2), w = nt*16 + (l&15).
__global__ __launch_bounds__(256) void prep_kernel(const float* __restrict__ w,
                                                   short* __restrict__ wf) {
    int e = blockIdx.x * 256 + threadIdx.x;   // 0..86015
    int f = e >> 9;
    int r = e & 511;
    int l = r >> 3, j = r & 7;
    int l15 = l & 15, lg = l >> 4;
    int kk = 4 * lg + (j & 3) + 16 * (j >> 2);
    int u, wc, woff, mul; float scale;
    if (f < 128) {
        int nt = f >> 3, s = f & 7;
        u = 32 * s + kk; wc = nt * 16 + l15; woff = 0;     mul = 256; scale = 0.0625f;
    } else if (f < 160) {
        int g = f - 128, nt = g >> 2, s = g & 3;
        u = 32 * s + kk; wc = nt * 16 + l15; woff = 65536; mul = 128; scale = 0.088388347648318447f;
    } else {
        int g = f - 160, nt = g >> 1, s = g & 1;
        u = 32 * s + kk; wc = nt * 16 + l15; woff = 81920; mul = 64;  scale = 0.125f;
    }
    wf[e] = f2bf(scale * w[woff + u * mul + wc]);
}

static __device__ __forceinline__ void gload_lds16(const void* g, void* l) {
    __builtin_amdgcn_global_load_lds(
        (const __attribute__((address_space(1))) unsigned int*)g,
        (__attribute__((address_space(3))) unsigned int*)l, 16, 0, 0);
}

__global__ __launch_bounds__(256) void lin_tile(const float* __restrict__ x,
                                                const short* __restrict__ wf,
                                                const float* __restrict__ bias,
                                                float* __restrict__ out) {
    __shared__ __align__(16) char smem[24576];
    const int tid  = threadIdx.x;
    const int lane = tid & 63;
    const int wv   = tid >> 6;
    const int l15  = lane & 15;
    const int lg   = lane >> 4;
    const int fam  = blockIdx.y;
    const long rowbase = (long)blockIdx.x * 16;
    const char* __restrict__ xb = (const char*)x + rowbase * 3840;
    float* __restrict__ outr = out + (rowbase + l15) * 960;
    const frag8* __restrict__ wfr = (const frag8*)wf;
    const int sw4 = (l15 & 7) << 4;

    // ---- stage this family's column slice (linear LDS dest, inverse-swizzled
    //      global source chunk: LDS[r][cc] = X[r][cc ^ (r&7)]) ----
    if (fam == 0) {              // cols 0..1023 B, C=64 chunks, 16 KB
        #pragma unroll
        for (int j = 0; j < 4; ++j) {
            int c  = j * 256 + tid;
            int r  = c >> 6;
            int cc = c & 63;
            int g  = cc ^ (r & 7);
            gload_lds16(xb + r * 3840 + (g << 4),
                        smem + (j * 256 + wv * 64) * 16);
        }
    } else if (fam == 1) {       // cols 1024..2559 B, C=96 chunks, 24 KB
        #pragma unroll
        for (int j = 0; j < 6; ++j) {
            int c  = j * 256 + tid;
            int r  = c / 96;
            int cc = c - r * 96;
            int g  = cc ^ (r & 7);
            gload_lds16(xb + r * 3840 + 1024 + (g << 4),
                        smem + (j * 256 + wv * 64) * 16);
        }
    } else {                     // cols 2560..3839 B, C=80 chunks, 20 KB
        #pragma unroll
        for (int j = 0; j < 5; ++j) {
            int c  = j * 256 + tid;
            int r  = c / 80;
            int cc = c - r * 80;
            int g  = cc ^ (r & 7);
            gload_lds16(xb + r * 3840 + 2560 + (g << 4),
                        smem + (j * 256 + wv * 64) * 16);
        }
    }
    __syncthreads();   // drains vmcnt(0): slice resident in LDS

    if (fam == 0) {
        // ===== block0: out cols 0..255, K=256; wave wv -> nt = 4wv..4wv+3 ====
        const char* sb = smem + l15 * 1024;
        #define LDC0(cc) (*(const f32x4*)(sb + (((cc) << 4) ^ sw4)))
        frag8 a0[8];
        #pragma unroll
        for (int s = 0; s < 8; ++s) {
            const f32x4 v0 = LDC0(8 * s + lg);
            const f32x4 v1 = LDC0(8 * s + 4 + lg);
            u32x4 t = { cvtpk(v0[0], v0[1]), cvtpk(v0[2], v0[3]),
                        cvtpk(v1[0], v1[1]), cvtpk(v1[2], v1[3]) };
            a0[s] = asfrag(t);
        }
        #pragma unroll
        for (int q = 0; q < 4; ++q) {
            const int nt = 4 * wv + q;
            f32x4 acc = {0.f, 0.f, 0.f, 0.f};
            #pragma unroll
            for (int s = 0; s < 8; ++s) {
                frag8 bw = wfr[(nt * 8 + s) * 64 + lane];
                acc = MFMA(bw, a0[s], acc);            // D[w][atom]
            }
            const f32x4 bv = *(const f32x4*)(bias + nt * 16 + 4 * lg);
            f32x4 st = {acc[0] + bv[0], acc[1] + bv[1], acc[2] + bv[2], acc[3] + bv[3]};
            *(f32x4*)(outr + nt * 16 + 4 * lg) = st;
        }
        #undef LDC0
    } else if (fam == 1) {
        // ===== block1: out cols 256..639 (col = 256+3u+i); nt = 2wv..2wv+1 ===
        const char* sb = smem + l15 * 1536;
        #define LDC1(cc) (*(const f32x4*)(sb + (((cc) << 4) ^ sw4)))
        u32x4 a1u[12];
        #pragma unroll
        for (int s = 0; s < 4; ++s) {
            #pragma unroll
            for (int h = 0; h < 2; ++h) {
                const int cb = 24 * s + 12 * h + 3 * lg;
                const f32x4 q0 = LDC1(cb);
                const f32x4 q1 = LDC1(cb + 1);
                const f32x4 q2 = LDC1(cb + 2);
                // frag elems (j0..j0+3) pairs -> packed regs 2h, 2h+1
                a1u[0 + s][2 * h]     = cvtpk(q0[0], q0[3]);
                a1u[0 + s][2 * h + 1] = cvtpk(q1[2], q2[1]);
                a1u[4 + s][2 * h]     = cvtpk(q0[1], q1[0]);
                a1u[4 + s][2 * h + 1] = cvtpk(q1[3], q2[2]);
                a1u[8 + s][2 * h]     = cvtpk(q0[2], q1[1]);
                a1u[8 + s][2 * h + 1] = cvtpk(q2[0], q2[3]);
            }
        }
        #undef LDC1
        #pragma unroll
        for (int q = 0; q < 2; ++q) {
            const int nt = 2 * wv + q;
            f32x4 c0 = {0.f,0.f,0.f,0.f}, c1 = {0.f,0.f,0.f,0.f}, c2 = {0.f,0.f,0.f,0.f};
            #pragma unroll
            for (int s = 0; s < 4; ++s) {
                frag8 bw = wfr[(128 + nt * 4 + s) * 64 + lane];
                c0 = MFMA(bw, asfrag(a1u[0 + s]), c0);
                c1 = MFMA(bw, asfrag(a1u[4 + s]), c1);
                c2 = MFMA(bw, asfrag(a1u[8 + s]), c2);
            }
            float* o = outr + 256 + 3 * (nt * 16 + 4 * lg);
            f32x4 v0 = {c0[0], c1[0], c2[0], c0[1]};
            f32x4 v1 = {c1[1], c2[1], c0[2], c1[2]};
            f32x4 v2 = {c2[2], c0[3], c1[3], c2[3]};
            *(f32x4*)(o)     = v0;
            *(f32x4*)(o + 4) = v1;
            *(f32x4*)(o + 8) = v2;
        }
    } else {
        // ===== block2: out cols 640..959 (col = 640+5u+i); nt = wv ===========
        const char* sb = smem + l15 * 1280;
        #define LDC2(cc) (*(const f32x4*)(sb + (((cc) << 4) ^ sw4)))
        u32x4 a2u[10];
        #pragma unroll
        for (int s = 0; s < 2; ++s) {
            #pragma unroll
            for (int h = 0; h < 2; ++h) {
                const int cb = 40 * s + 20 * h + 5 * lg;
                const f32x4 q0 = LDC2(cb);
                const f32x4 q1 = LDC2(cb + 1);
                const f32x4 q2 = LDC2(cb + 2);
                const f32x4 q3 = LDC2(cb + 3);
                const f32x4 q4 = LDC2(cb + 4);
                a2u[0 + s][2 * h]     = cvtpk(q0[0], q1[1]);
                a2u[0 + s][2 * h + 1] = cvtpk(q2[2], q3[3]);
                a2u[2 + s][2 * h]     = cvtpk(q0[1], q1[2]);
                a2u[2 + s][2 * h + 1] = cvtpk(q2[3], q4[0]);
                a2u[4 + s][2 * h]     = cvtpk(q0[2], q1[3]);
                a2u[4 + s][2 * h + 1] = cvtpk(q3[0], q4[1]);
                a2u[6 + s][2 * h]     = cvtpk(q0[3], q2[0]);
                a2u[6 + s][2 * h + 1] = cvtpk(q3[1], q4[2]);
                a2u[8 + s][2 * h]     = cvtpk(q1[0], q2[1]);
                a2u[8 + s][2 * h + 1] = cvtpk(q3[2], q4[3]);
            }
        }
        #undef LDC2
        {
            const int nt = wv;
            f32x4 c0 = {0.f,0.f,0.f,0.f}, c1 = {0.f,0.f,0.f,0.f}, c2 = {0.f,0.f,0.f,0.f},
                  c3 = {0.f,0.f,0.f,0.f}, c4 = {0.f,0.f,0.f,0.f};
            #pragma unroll
            for (int s = 0; s < 2; ++s) {
                frag8 bw = wfr[(160 + nt * 2 + s) * 64 + lane];
                c0 = MFMA(bw, asfrag(a2u[0 + s]), c0);
                c1 = MFMA(bw, asfrag(a2u[2 + s]), c1);
                c2 = MFMA(bw, asfrag(a2u[4 + s]), c2);
                c3 = MFMA(bw, asfrag(a2u[6 + s]), c3);
                c4 = MFMA(bw, asfrag(a2u[8 + s]), c4);
            }
            float* o = outr + 640 + 5 * (nt * 16 + 4 * lg);
            f32x4 v0 = {c0[0], c1[0], c2[0], c3[0]};
            f32x4 v1 = {c4[0], c0[1], c1[1], c2[1]};
            f32x4 v2 = {c3[1], c4[1], c0[2], c1[2]};
            f32x4 v3 = {c2[2], c3[2], c4[2], c0[3]};
            f32x4 v4 = {c1[3], c2[3], c3[3], c4[3]};
            *(f32x4*)(o)      = v0;
            *(f32x4*)(o + 4)  = v1;
            *(f32x4*)(o + 8)  = v2;
            *(f32x4*)(o + 12) = v3;
            *(f32x4*)(o + 16) = v4;
        }
    }
}

extern "C" void kernel_launch(void* const* d_in, const int* in_sizes, int n_in,
                              void* d_out, int out_size, void* d_ws, size_t ws_size,
                              hipStream_t stream) {
    const float* x = (const float*)d_in[0];
    const float* w = (const float*)d_in[1];
    const float* b = (const float*)d_in[2];
    float* out = (float*)d_out;
    short* wf  = (short*)d_ws;          // 86016 bf16 = 172032 B of scratch

    hipLaunchKernelGGL(prep_kernel, dim3(336), dim3(256), 0, stream, w, wf);
    // 12500 16-row tiles x 3 irrep families
    hipLaunchKernelGGL(lin_tile, dim3(12500, 3), dim3(256), 0, stream,
                       x, wf, b, out);
}

// Round 6
// 353.660 us; speedup vs baseline: 1.1238x; 1.1238x over previous
//
#include <hip/hip_runtime.h>

// irreps linear: 256x0e + 128x1o + 64x2e, shared weights, bias on 0e.
// x: (200000, 960) f32; w: 86016 f32; b: 256 f32; out: (200000, 960) f32.
//
// Round 6 = Round 5 + LDS OUTPUT staging: compute lanes ds_write their
// (validated R2-map) 16B output pieces into the reused 24KB LDS tile
// (row-XOR chunk swizzle), barrier, then all 256 threads store the tile
// with fully-contiguous 1024B-per-instruction global stores (mirror of the
// global_load_lds input staging). Theory: 64B scattered store segments were
// the ~2x-off-BW limiter common to rounds 1-5.

typedef short frag8 __attribute__((ext_vector_type(8)));   // 8 bf16
typedef float f32x4 __attribute__((ext_vector_type(4)));
typedef unsigned int u32;
typedef u32 u32x4 __attribute__((ext_vector_type(4)));

static __device__ __forceinline__ short f2bf(float f) {   // prep kernel only
    union { float f; unsigned u; } v; v.f = f;
    unsigned r = (v.u + 0x7FFFu + ((v.u >> 16) & 1u)) >> 16;  // RNE
    return (short)r;
}

// 2 f32 -> one u32 holding 2 bf16 (lo = first arg), single VALU op.
static __device__ __forceinline__ u32 cvtpk(float lo, float hi) {
    u32 r;
    asm("v_cvt_pk_bf16_f32 %0, %1, %2" : "=v"(r) : "v"(lo), "v"(hi));
    return r;
}

static __device__ __forceinline__ frag8 asfrag(u32x4 u) {
    union { u32x4 u; frag8 f; } t; t.u = u; return t.f;
}

#define MFMA(a, b, c) __builtin_amdgcn_mfma_f32_16x16x32_bf16((a), (b), (c), 0, 0, 0)

// ---- weight prep: unchanged (validated rounds 1-5). frag f, lane l, reg j:
// k = 32*s + 4*(l>>4) + (j&3) + 16*(j>>2), w = nt*16 + (l&15).
__global__ __launch_bounds__(256) void prep_kernel(const float* __restrict__ w,
                                                   short* __restrict__ wf) {
    int e = blockIdx.x * 256 + threadIdx.x;   // 0..86015
    int f = e >> 9;
    int r = e & 511;
    int l = r >> 3, j = r & 7;
    int l15 = l & 15, lg = l >> 4;
    int kk = 4 * lg + (j & 3) + 16 * (j >> 2);
    int u, wc, woff, mul; float scale;
    if (f < 128) {
        int nt = f >> 3, s = f & 7;
        u = 32 * s + kk; wc = nt * 16 + l15; woff = 0;     mul = 256; scale = 0.0625f;
    } else if (f < 160) {
        int g = f - 128, nt = g >> 2, s = g & 3;
        u = 32 * s + kk; wc = nt * 16 + l15; woff = 65536; mul = 128; scale = 0.088388347648318447f;
    } else {
        int g = f - 160, nt = g >> 1, s = g & 1;
        u = 32 * s + kk; wc = nt * 16 + l15; woff = 81920; mul = 64;  scale = 0.125f;
    }
    wf[e] = f2bf(scale * w[woff + u * mul + wc]);
}

static __device__ __forceinline__ void gload_lds16(const void* g, void* l) {
    __builtin_amdgcn_global_load_lds(
        (const __attribute__((address_space(1))) unsigned int*)g,
        (__attribute__((address_space(3))) unsigned int*)l, 16, 0, 0);
}

__global__ __launch_bounds__(256) void lin_tile(const float* __restrict__ x,
                                                const short* __restrict__ wf,
                                                const float* __restrict__ bias,
                                                float* __restrict__ out) {
    __shared__ __align__(16) char smem[24576];
    const int tid  = threadIdx.x;
    const int lane = tid & 63;
    const int wv   = tid >> 6;
    const int l15  = lane & 15;
    const int lg   = lane >> 4;
    const int fam  = blockIdx.y;
    const long rowbase = (long)blockIdx.x * 16;
    const char* __restrict__ xb = (const char*)x + rowbase * 3840;
    char* __restrict__ ob = (char*)out + rowbase * 3840;   // tile out base
    const frag8* __restrict__ wfr = (const frag8*)wf;
    const int sw4 = (l15 & 7) << 4;

    // ---- stage this family's column slice (linear LDS dest, inverse-swizzled
    //      global source chunk: LDS[r][cc] = X[r][cc ^ (r&7)]) ----
    if (fam == 0) {              // cols 0..1023 B, C=64 chunks, 16 KB
        #pragma unroll
        for (int j = 0; j < 4; ++j) {
            int c  = j * 256 + tid;
            int r  = c >> 6;
            int cc = c & 63;
            int g  = cc ^ (r & 7);
            gload_lds16(xb + r * 3840 + (g << 4),
                        smem + (j * 256 + wv * 64) * 16);
        }
    } else if (fam == 1) {       // cols 1024..2559 B, C=96 chunks, 24 KB
        #pragma unroll
        for (int j = 0; j < 6; ++j) {
            int c  = j * 256 + tid;
            int r  = c / 96;
            int cc = c - r * 96;
            int g  = cc ^ (r & 7);
            gload_lds16(xb + r * 3840 + 1024 + (g << 4),
                        smem + (j * 256 + wv * 64) * 16);
        }
    } else {                     // cols 2560..3839 B, C=80 chunks, 20 KB
        #pragma unroll
        for (int j = 0; j < 5; ++j) {
            int c  = j * 256 + tid;
            int r  = c / 80;
            int cc = c - r * 80;
            int g  = cc ^ (r & 7);
            gload_lds16(xb + r * 3840 + 2560 + (g << 4),
                        smem + (j * 256 + wv * 64) * 16);
        }
    }
    __syncthreads();   // drains vmcnt(0): slice resident in LDS

    if (fam == 0) {
        // ===== block0: out cols 0..255, K=256; wave wv -> nt = 4wv..4wv+3 ====
        const char* sb = smem + l15 * 1024;
        #define LDC0(cc) (*(const f32x4*)(sb + (((cc) << 4) ^ sw4)))
        frag8 a0[8];
        #pragma unroll
        for (int s = 0; s < 8; ++s) {
            const f32x4 v0 = LDC0(8 * s + lg);
            const f32x4 v1 = LDC0(8 * s + 4 + lg);
            u32x4 t = { cvtpk(v0[0], v0[1]), cvtpk(v0[2], v0[3]),
                        cvtpk(v1[0], v1[1]), cvtpk(v1[2], v1[3]) };
            a0[s] = asfrag(t);
        }
        #undef LDC0
        f32x4 st[4];
        #pragma unroll
        for (int q = 0; q < 4; ++q) {
            const int nt = 4 * wv + q;
            f32x4 acc = {0.f, 0.f, 0.f, 0.f};
            #pragma unroll
            for (int s = 0; s < 8; ++s) {
                frag8 bw = wfr[(nt * 8 + s) * 64 + lane];
                acc = MFMA(bw, a0[s], acc);            // D[w][atom]
            }
            const f32x4 bv = *(const f32x4*)(bias + nt * 16 + 4 * lg);
            st[q][0] = acc[0] + bv[0]; st[q][1] = acc[1] + bv[1];
            st[q][2] = acc[2] + bv[2]; st[q][3] = acc[3] + bv[3];
        }
        __syncthreads();   // all input LDS reads done; safe to overwrite
        #pragma unroll
        for (int q = 0; q < 4; ++q) {
            const int g0 = (4 * wv + q) * 4 + lg;       // lane's 16B chunk
            *(f32x4*)(smem + l15 * 1024 + (((g0 ^ (l15 & 7))) << 4)) = st[q];
        }
        __syncthreads();
        #pragma unroll
        for (int j = 0; j < 4; ++j) {
            int c = j * 256 + tid;
            int r = c >> 6;
            int g = c & 63;
            f32x4 v = *(const f32x4*)(smem + r * 1024 + ((g ^ (r & 7)) << 4));
            *(f32x4*)(ob + (long)r * 3840 + (g << 4)) = v;
        }
    } else if (fam == 1) {
        // ===== block1: out cols 256..639 (col = 256+3u+i); nt = 2wv..2wv+1 ===
        const char* sb = smem + l15 * 1536;
        #define LDC1(cc) (*(const f32x4*)(sb + (((cc) << 4) ^ sw4)))
        u32x4 a1u[12];
        #pragma unroll
        for (int s = 0; s < 4; ++s) {
            #pragma unroll
            for (int h = 0; h < 2; ++h) {
                const int cb = 24 * s + 12 * h + 3 * lg;
                const f32x4 q0 = LDC1(cb);
                const f32x4 q1 = LDC1(cb + 1);
                const f32x4 q2 = LDC1(cb + 2);
                a1u[0 + s][2 * h]     = cvtpk(q0[0], q0[3]);
                a1u[0 + s][2 * h + 1] = cvtpk(q1[2], q2[1]);
                a1u[4 + s][2 * h]     = cvtpk(q0[1], q1[0]);
                a1u[4 + s][2 * h + 1] = cvtpk(q1[3], q2[2]);
                a1u[8 + s][2 * h]     = cvtpk(q0[2], q1[1]);
                a1u[8 + s][2 * h + 1] = cvtpk(q2[0], q2[3]);
            }
        }
        #undef LDC1
        f32x4 sv[2][3];
        #pragma unroll
        for (int q = 0; q < 2; ++q) {
            const int nt = 2 * wv + q;
            f32x4 c0 = {0.f,0.f,0.f,0.f}, c1 = {0.f,0.f,0.f,0.f}, c2 = {0.f,0.f,0.f,0.f};
            #pragma unroll
            for (int s = 0; s < 4; ++s) {
                frag8 bw = wfr[(128 + nt * 4 + s) * 64 + lane];
                c0 = MFMA(bw, asfrag(a1u[0 + s]), c0);
                c1 = MFMA(bw, asfrag(a1u[4 + s]), c1);
                c2 = MFMA(bw, asfrag(a1u[8 + s]), c2);
            }
            sv[q][0] = (f32x4){c0[0], c1[0], c2[0], c0[1]};
            sv[q][1] = (f32x4){c1[1], c2[1], c0[2], c1[2]};
            sv[q][2] = (f32x4){c2[2], c0[3], c1[3], c2[3]};
        }
        __syncthreads();
        #pragma unroll
        for (int q = 0; q < 2; ++q) {
            const int g0 = 3 * ((2 * wv + q) * 4 + lg);  // 3 consecutive chunks
            char* wb = smem + l15 * 1536;
            #pragma unroll
            for (int i = 0; i < 3; ++i)
                *(f32x4*)(wb + (((g0 + i) ^ (l15 & 7)) << 4)) = sv[q][i];
        }
        __syncthreads();
        #pragma unroll
        for (int j = 0; j < 6; ++j) {
            int c = j * 256 + tid;
            int r = c / 96;
            int g = c - r * 96;
            f32x4 v = *(const f32x4*)(smem + r * 1536 + ((g ^ (r & 7)) << 4));
            *(f32x4*)(ob + (long)r * 3840 + 1024 + (g << 4)) = v;
        }
    } else {
        // ===== block2: out cols 640..959 (col = 640+5u+i); nt = wv ===========
        const char* sb = smem + l15 * 1280;
        #define LDC2(cc) (*(const f32x4*)(sb + (((cc) << 4) ^ sw4)))
        u32x4 a2u[10];
        #pragma unroll
        for (int s = 0; s < 2; ++s) {
            #pragma unroll
            for (int h = 0; h < 2; ++h) {
                const int cb = 40 * s + 20 * h + 5 * lg;
                const f32x4 q0 = LDC2(cb);
                const f32x4 q1 = LDC2(cb + 1);
                const f32x4 q2 = LDC2(cb + 2);
                const f32x4 q3 = LDC2(cb + 3);
                const f32x4 q4 = LDC2(cb + 4);
                a2u[0 + s][2 * h]     = cvtpk(q0[0], q1[1]);
                a2u[0 + s][2 * h + 1] = cvtpk(q2[2], q3[3]);
                a2u[2 + s][2 * h]     = cvtpk(q0[1], q1[2]);
                a2u[2 + s][2 * h + 1] = cvtpk(q2[3], q4[0]);
                a2u[4 + s][2 * h]     = cvtpk(q0[2], q1[3]);
                a2u[4 + s][2 * h + 1] = cvtpk(q3[0], q4[1]);
                a2u[6 + s][2 * h]     = cvtpk(q0[3], q2[0]);
                a2u[6 + s][2 * h + 1] = cvtpk(q3[1], q4[2]);
                a2u[8 + s][2 * h]     = cvtpk(q1[0], q2[1]);
                a2u[8 + s][2 * h + 1] = cvtpk(q3[2], q4[3]);
            }
        }
        #undef LDC2
        f32x4 sv[5];
        {
            const int nt = wv;
            f32x4 c0 = {0.f,0.f,0.f,0.f}, c1 = {0.f,0.f,0.f,0.f}, c2 = {0.f,0.f,0.f,0.f},
                  c3 = {0.f,0.f,0.f,0.f}, c4 = {0.f,0.f,0.f,0.f};
            #pragma unroll
            for (int s = 0; s < 2; ++s) {
                frag8 bw = wfr[(160 + nt * 2 + s) * 64 + lane];
                c0 = MFMA(bw, asfrag(a2u[0 + s]), c0);
                c1 = MFMA(bw, asfrag(a2u[2 + s]), c1);
                c2 = MFMA(bw, asfrag(a2u[4 + s]), c2);
                c3 = MFMA(bw, asfrag(a2u[6 + s]), c3);
                c4 = MFMA(bw, asfrag(a2u[8 + s]), c4);
            }
            sv[0] = (f32x4){c0[0], c1[0], c2[0], c3[0]};
            sv[1] = (f32x4){c4[0], c0[1], c1[1], c2[1]};
            sv[2] = (f32x4){c3[1], c4[1], c0[2], c1[2]};
            sv[3] = (f32x4){c2[2], c3[2], c4[2], c0[3]};
            sv[4] = (f32x4){c1[3], c2[3], c3[3], c4[3]};
        }
        __syncthreads();
        {
            const int g0 = 5 * (wv * 4 + lg);            // 5 consecutive chunks
            char* wb = smem + l15 * 1280;
            #pragma unroll
            for (int i = 0; i < 5; ++i)
                *(f32x4*)(wb + (((g0 + i) ^ (l15 & 7)) << 4)) = sv[i];
        }
        __syncthreads();
        #pragma unroll
        for (int j = 0; j < 5; ++j) {
            int c = j * 256 + tid;
            int r = c / 80;
            int g = c - r * 80;
            f32x4 v = *(const f32x4*)(smem + r * 1280 + ((g ^ (r & 7)) << 4));
            *(f32x4*)(ob + (long)r * 3840 + 2560 + (g << 4)) = v;
        }
    }
}

extern "C" void kernel_launch(void* const* d_in, const int* in_sizes, int n_in,
                              void* d_out, int out_size, void* d_ws, size_t ws_size,
                              hipStream_t stream) {
    const float* x = (const float*)d_in[0];
    const float* w = (const float*)d_in[1];
    const float* b = (const float*)d_in[2];
    float* out = (float*)d_out;
    short* wf  = (short*)d_ws;          // 86016 bf16 = 172032 B of scratch

    hipLaunchKernelGGL(prep_kernel, dim3(336), dim3(256), 0, stream, w, wf);
    // 12500 16-row tiles x 3 irrep families
    hipLaunchKernelGGL(lin_tile, dim3(12500, 3), dim3(256), 0, stream,
                       x, wf, b, out);
}